// Round 2
// baseline (76.924 us; speedup 1.0000x reference)
//
#include <hip/hip_runtime.h>
#include <math.h>

#define N_QUBITS 11
#define DIM 2048

// ---------------------------------------------------------------------------
// TRANSFER-MATRIX FORMULATION, v2.1 — fused-tail + folded-head tables.
//
//   out[j] = Re[ u(n0) · M1(b1) · M2(b2) · M3(b3) · ... · M10(b10) · (1,1)^T ]
// with b = j ^ (j<<1)  (b_q = j_q ^ j_{q-1}),  j = w*1024 + L*16 + n.
//   b0=n0, b1=n1^n0, b2=n2^n1, b3=n3^n2, b4=L0^n3,
//   b{5+k}=z_k where z=L^(L>>1), b10=w^L5.
//
//  * W6[64]  = M5·M6·M7·M8·M9·M10·(1,1) per (b10..b5) — whole per-lane tail
//    collapses to ONE ds_read_b128 (was 12 reads + 6 chain steps).
//  * UM3[8]  = u(n0)·M1(n1^n0)·M2(b2) — q2 folded into output rows.
//  * UM3 + both K[3] rows hoisted to registers; only K[4] read inline.
//    Per-lane LDS traffic: 44 -> 17 ds_read_b128. Chain steps: 21 -> 6.
//
// v2.1 FIX: Phase-2 K-table build now covers EXACTLY the 22 (q,b) entries
// (wave0: b=0, wave1: b=1, q=0..10 each). v2 (and latently v1) launched 44
// threads with q=t>>1 up to 21, writing up to 351 floats past K[11][2][8] —
// benign under v1's LDS layout, but with W6/UM3 added the compiler may place
// live tables (C1/G2/W6) after K, and the OOB stores stomped them WHILE
// phase-2 readers were consuming them -> NaN output. Exact-cover guard, 0 OOB.
// ---------------------------------------------------------------------------

struct cT { float r0, i0, r1, i1; };   // 2-entry complex column vector

static __device__ __forceinline__
cT step(const float* Krow, const cT& T)
{
    const float4 A = *(const float4*)(Krow);      // d0, d1
    const float4 B = *(const float4*)(Krow + 4);  // e0, e1
    cT o;
    o.r0 = A.x * T.r0 - A.y * T.i0 + A.z * T.r1 - A.w * T.i1;
    o.i0 = A.x * T.i0 + A.y * T.r0 + A.z * T.i1 + A.w * T.r1;
    o.r1 = B.x * T.r0 - B.y * T.i0 + B.z * T.r1 - B.w * T.i1;
    o.i1 = B.x * T.i0 + B.y * T.r0 + B.z * T.i1 + B.w * T.r1;
    return o;
}

static __device__ __forceinline__
cT stepv(const float4 A, const float4 B, const cT& T)
{
    cT o;
    o.r0 = A.x * T.r0 - A.y * T.i0 + A.z * T.r1 - A.w * T.i1;
    o.i0 = A.x * T.i0 + A.y * T.r0 + A.z * T.i1 + A.w * T.r1;
    o.r1 = B.x * T.r0 - B.y * T.i0 + B.z * T.r1 - B.w * T.i1;
    o.i1 = B.x * T.i0 + B.y * T.r0 + B.z * T.i1 + B.w * T.r1;
    return o;
}

static __device__ __forceinline__
float redot(const float4& m, const cT& T)
{   // Re( m(0)*T0 + m(1)*T1 )
    return m.x * T.r0 - m.y * T.i0 + m.z * T.r1 - m.w * T.i1;
}

__global__ __launch_bounds__(128)
void pqc_sim_kernel(const float* __restrict__ theta,
                    const int* __restrict__ positions,
                    float* __restrict__ out)
{
    __shared__ float  C1[N_QUBITS][4];     // layer-1 col0: c(0)re,im, c(1)re,im
    __shared__ float  G2[N_QUBITS][8];     // layer-2 full 2x2 complex
    __shared__ float  K[N_QUBITS][2][8];   // transfer coeffs per (q, b)
    __shared__ float4 W6[64];              // fused tail: M5..M10·(1,1) per (b10..b5)
    __shared__ float4 UM3[8];              // u(n0)·M1(n1^n0)·M2(b2), idx = 4n0+2n1+b2

    const int t   = threadIdx.x;
    const int b   = blockIdx.x;
    const int pos = positions[b];

    // ---- Phase 1: gates (wave0: layer 0, wave1: layer 1; 11 threads each) ----
    if ((t & 63) < N_QUBITS) {
        const int l = t >> 6;
        const int q = t & 63;
        const float* th = theta + (((size_t)pos * 2 + l) * (3 * N_QUBITS)) + 3 * q;
        const float a  = th[0] * 0.5f;
        const float bb = th[1] * 0.5f;
        const float g  = th[2] * 0.5f;
        float sa, ca, sb, cb, sg, cg;
        sincosf(a,  &sa, &ca);
        sincosf(bb, &sb, &cb);
        sincosf(g,  &sg, &cg);
        const float m00r =  cb * ca, m00i =  sb * sa;
        const float m01r = -sb * ca, m01i = -cb * sa;
        const float m10r =  sb * ca, m10i = -cb * sa;
        const float m11r =  cb * ca, m11i = -sb * sa;
        const float u00r = m00r * cg + m00i * sg, u00i = m00i * cg - m00r * sg;
        const float u01r = m01r * cg + m01i * sg, u01i = m01i * cg - m01r * sg;
        const float u10r = m10r * cg - m10i * sg, u10i = m10i * cg + m10r * sg;
        const float u11r = m11r * cg - m11i * sg, u11i = m11i * cg + m11r * sg;
        if (l) {
            G2[q][0] = u00r; G2[q][1] = u00i; G2[q][2] = u01r; G2[q][3] = u01i;
            G2[q][4] = u10r; G2[q][5] = u10i; G2[q][6] = u11r; G2[q][7] = u11i;
        } else {
            C1[q][0] = u00r; C1[q][1] = u00i;   // c_q(0)
            C1[q][2] = u10r; C1[q][3] = u10i;   // c_q(1)
        }
    }
    __syncthreads();

    // ---- Phase 2: K table — EXACT cover: wave0 builds b=0, wave1 builds b=1,
    // q = 0..10 each. (22 entries total, zero out-of-bounds.) ----
    if ((t & 63) < N_QUBITS) {
        const int q  = t & 63;
        const int bb = t >> 6;
        const float v0r = G2[q][bb * 4 + 0], v0i = G2[q][bb * 4 + 1];
        const float v1r = G2[q][bb * 4 + 2], v1i = G2[q][bb * 4 + 3];
        const float c0r = C1[q][0], c0i = C1[q][1];
        const float c1r = C1[q][2], c1i = C1[q][3];
        K[q][bb][0] = v0r * c0r - v0i * c0i;   // d0 = V[b,0]*c(0)
        K[q][bb][1] = v0r * c0i + v0i * c0r;
        K[q][bb][2] = v1r * c1r - v1i * c1i;   // d1 = V[b,1]*c(1)
        K[q][bb][3] = v1r * c1i + v1i * c1r;
        K[q][bb][4] = v0r * c1r - v0i * c1i;   // e0 = V[b,0]*c(1)
        K[q][bb][5] = v0r * c1i + v0i * c1r;
        K[q][bb][6] = v1r * c0r - v1i * c0i;   // e1 = V[b,1]*c(0)
        K[q][bb][7] = v1r * c0i + v1i * c0r;
    }
    __syncthreads();

    // ---- Phase 3: fused tables ----
    // W6[e], e = (b10<<5)|(b9<<4)|(b8<<3)|(b7<<2)|(b6<<1)|b5 : 32 entries/wave
    if ((t & 63) < 32) {
        const int e = (t & 63) | ((t >> 6) << 5);   // 0..63
        const float* Kr = &K[10][e >> 5][0];
        const float4 A = *(const float4*)(Kr);
        const float4 B = *(const float4*)(Kr + 4);
        cT T;
        T.r0 = A.x + A.z;  T.i0 = A.y + A.w;        // M10 · (1,1)
        T.r1 = B.x + B.z;  T.i1 = B.y + B.w;
        T = step(&K[9][(e >> 4) & 1][0], T);
        T = step(&K[8][(e >> 3) & 1][0], T);
        T = step(&K[7][(e >> 2) & 1][0], T);
        T = step(&K[6][(e >> 1) & 1][0], T);
        T = step(&K[5][e & 1][0], T);
        W6[e] = make_float4(T.r0, T.i0, T.r1, T.i1);
    } else if (t >= 32 && t < 40) {
        // UM3[e], e = 4*n0 + 2*n1 + b2 = u(n0) · M1(n1^n0) · M2(b2)
        const int e  = t - 32;
        const int n0 = e >> 2, n1 = (e >> 1) & 1, b2 = e & 1;
        const int b1 = n1 ^ n0;
        const float u0r = K[0][n0][0], u0i = K[0][n0][1];
        const float u1r = K[0][n0][2], u1i = K[0][n0][3];
        // r = u · M1(b1),  M = [[d0,d1],[e0,e1]]
        const float d0r = K[1][b1][0], d0i = K[1][b1][1];
        const float d1r = K[1][b1][2], d1i = K[1][b1][3];
        const float e0r = K[1][b1][4], e0i = K[1][b1][5];
        const float e1r = K[1][b1][6], e1i = K[1][b1][7];
        const float r0r = u0r * d0r - u0i * d0i + u1r * e0r - u1i * e0i;
        const float r0i = u0r * d0i + u0i * d0r + u1r * e0i + u1i * e0r;
        const float r1r = u0r * d1r - u0i * d1i + u1r * e1r - u1i * e1i;
        const float r1i = u0r * d1i + u0i * d1r + u1r * e1i + u1i * e1r;
        // s = r · M2(b2)
        const float f0r = K[2][b2][0], f0i = K[2][b2][1];
        const float f1r = K[2][b2][2], f1i = K[2][b2][3];
        const float g0r = K[2][b2][4], g0i = K[2][b2][5];
        const float g1r = K[2][b2][6], g1i = K[2][b2][7];
        const float s0r = r0r * f0r - r0i * f0i + r1r * g0r - r1i * g0i;
        const float s0i = r0r * f0i + r0i * f0r + r1r * g0i + r1i * g0r;
        const float s1r = r0r * f1r - r0i * f1i + r1r * g1r - r1i * g1i;
        const float s1i = r0r * f1i + r0i * f1r + r1r * g1i + r1i * g1r;
        UM3[e] = make_float4(s0r, s0i, s1r, s1i);
    }
    __syncthreads();

    // ---- Main: per-lane, 1 table read + 6 steps + 16 redots, no barriers ----
    const int w = t >> 6, L = t & 63;
    const int z = L ^ (L >> 1);
    const int widx = ((w ^ (L >> 5)) << 5) | (z & 31);
    const float4 Tv = W6[widx];
    cT T; T.r0 = Tv.x; T.i0 = Tv.y; T.r1 = Tv.z; T.i1 = Tv.w;

    // hoisted row tables (broadcast reads, then pure-register inner loop)
    const float4 m0 = UM3[0], m1 = UM3[1], m2 = UM3[2], m3 = UM3[3];
    const float4 m4 = UM3[4], m5 = UM3[5], m6 = UM3[6], m7 = UM3[7];
    const float4 k3A0 = *(const float4*)&K[3][0][0], k3B0 = *(const float4*)&K[3][0][4];
    const float4 k3A1 = *(const float4*)&K[3][1][0], k3B1 = *(const float4*)&K[3][1][4];

    const int L0 = L & 1;
    const float* k4a = &K[4][L0][0];       // n3=0: b4 = L0
    const float* k4b = &K[4][L0 ^ 1][0];   // n3=1: b4 = L0^1
    float* orow = out + (size_t)b * DIM + w * 1024 + L * 16;

    // n3 = 0
    {
        const cT T4 = step(k4a, T);
        {   // n2 = 0: b3 = 0; rows: x:UM3[0] y:UM3[4] z:UM3[3] w:UM3[7]
            const cT T3 = stepv(k3A0, k3B0, T4);
            float4 o;
            o.x = redot(m0, T3);  o.y = redot(m4, T3);
            o.z = redot(m3, T3);  o.w = redot(m7, T3);
            *(float4*)(orow + 0) = o;
        }
        {   // n2 = 1: b3 = 1; rows: x:UM3[1] y:UM3[5] z:UM3[2] w:UM3[6]
            const cT T3 = stepv(k3A1, k3B1, T4);
            float4 o;
            o.x = redot(m1, T3);  o.y = redot(m5, T3);
            o.z = redot(m2, T3);  o.w = redot(m6, T3);
            *(float4*)(orow + 4) = o;
        }
    }
    // n3 = 1
    {
        const cT T4 = step(k4b, T);
        {   // n2 = 0: b3 = 1
            const cT T3 = stepv(k3A1, k3B1, T4);
            float4 o;
            o.x = redot(m0, T3);  o.y = redot(m4, T3);
            o.z = redot(m3, T3);  o.w = redot(m7, T3);
            *(float4*)(orow + 8) = o;
        }
        {   // n2 = 1: b3 = 0
            const cT T3 = stepv(k3A0, k3B0, T4);
            float4 o;
            o.x = redot(m1, T3);  o.y = redot(m5, T3);
            o.z = redot(m2, T3);  o.w = redot(m6, T3);
            *(float4*)(orow + 12) = o;
        }
    }
}

extern "C" void kernel_launch(void* const* d_in, const int* in_sizes, int n_in,
                              void* d_out, int out_size, void* d_ws, size_t ws_size,
                              hipStream_t stream)
{
    const float* theta     = (const float*)d_in[0];
    const int*   positions = (const int*)d_in[1];
    float*       out       = (float*)d_out;
    const int B = in_sizes[1];   // 4096

    pqc_sim_kernel<<<B, 128, 0, stream>>>(theta, positions, out);
}